// Round 2
// baseline (32239.252 us; speedup 1.0000x reference)
//
#include <hip/hip_runtime.h>
#include <math.h>

#define B_ 128
#define T_ 512
#define I_ 128
#define H_ 1024
#define G4_ 4096
#define KE_ 1152   // I_ + H_
#define NBLK 256
#define LSTR 1160  // padded LDS row stride in elements (+8 -> 2-way bank alias = free)
#define ENCOFF ((long)B_*T_*I_)

typedef short short8 __attribute__((ext_vector_type(8)));
typedef float f32x4 __attribute__((ext_vector_type(4)));

__device__ __forceinline__ unsigned short f2bf(float f){
  unsigned int x; __builtin_memcpy(&x,&f,4);
  x += 0x7fffu + ((x>>16)&1u);
  return (unsigned short)(x>>16);
}
__device__ __forceinline__ float sigm(float x){ return 1.f/(1.f+__expf(-x)); }
__device__ __forceinline__ float tanh_(float x){ return 1.f - 2.f/(1.f+__expf(2.f*x)); }

// ---------------- prepass kernels ----------------

__global__ void k_f32_to_bf16(const float* __restrict__ src, unsigned short* __restrict__ dst, int n){
  int i = blockIdx.x*256 + threadIdx.x;
  if(i < n) dst[i] = f2bf(src[i]);
}

__global__ void k_build_wcat(const float* __restrict__ Wih, const float* __restrict__ Whh,
                             unsigned short* __restrict__ out){
  int n = blockIdx.y;
  int k = blockIdx.x*256 + threadIdx.x;
  if(k < KE_){
    float v = (k < I_) ? Wih[n*I_ + k] : Whh[n*H_ + (k - I_)];
    out[n*KE_ + k] = f2bf(v);
  }
}

__global__ void k_build_weff(const float* __restrict__ Wih, const float* __restrict__ Whh,
                             const float* __restrict__ linW, unsigned short* __restrict__ out){
  int n = blockIdx.y;
  int k = blockIdx.x*256 + threadIdx.x;  // < 1024
  float acc = Whh[n*H_ + k];
  for(int j=0;j<I_;j++) acc += Wih[n*I_ + j] * linW[j*H_ + k];
  out[n*H_ + k] = f2bf(acc);
}

__global__ void k_build_bias(const float* __restrict__ ebih, const float* __restrict__ ebhh,
                             const float* __restrict__ dbih, const float* __restrict__ dbhh,
                             const float* __restrict__ dWih, const float* __restrict__ linb,
                             float* __restrict__ encb, float* __restrict__ decb, float* __restrict__ decbeff){
  int n = blockIdx.x*256 + threadIdx.x;  // < 4096
  encb[n] = ebih[n] + ebhh[n];
  float db = dbih[n] + dbhh[n];
  decb[n] = db;
  float acc = db;
  for(int j=0;j<I_;j++) acc += linb[j]*dWih[n*I_ + j];
  decbeff[n] = acc;
}

__global__ void k_init_state(unsigned short* __restrict__ h0, unsigned* __restrict__ cnt){
  int i = blockIdx.x*256 + threadIdx.x;  // covers B_*H_
  if(i < B_*H_) h0[i] = 0;
  if(i == 0) *cnt = 0u;
}

// ---------------- persistent cooperative kernel ----------------
// 256 blocks x 256 threads, 1 block/CU. Block b owns h-cols [4b,4b+4) and the
// 16 gate-rows {g*1024 + 4b + c}. c/h state in registers (keeper lanes lr<4).
// Weight strip staged in LDS; grid barrier per step.
__global__ __launch_bounds__(256, 1) void k_persist(
    const unsigned short* __restrict__ encW,   // [4096][1152]
    const unsigned short* __restrict__ decW,   // [4096][1152]
    const unsigned short* __restrict__ weff,   // [4096][1024]
    const unsigned short* __restrict__ xbf,    // [B][T][I]
    unsigned short* __restrict__ hb0,          // [B][H]
    unsigned short* __restrict__ hb1,          // [B][H]
    const float* __restrict__ encb, const float* __restrict__ decb, const float* __restrict__ decbe,
    const int* __restrict__ lengths, const int* __restrict__ tfmask,
    const unsigned short* __restrict__ linwb,  // [128][1024]
    const float* __restrict__ linb,            // [128]
    float* __restrict__ dout,
    unsigned* __restrict__ cnt)
{
  __shared__ __align__(16) unsigned short wlds[16*LSTR];

  const int b   = blockIdx.x;
  const int tid = threadIdx.x;
  const int w   = tid >> 6;
  const int l   = tid & 63;
  const int lr  = l & 15;
  const int lq  = l >> 4;
  const int hc0 = b * 4;
  const int hc  = hc0 + (l & 3);

  // projection tile assignment: tile j -> block 4j+(j&3), wave j&3
  const int jj = b >> 2;
  const bool projb = ((b & 3) == (jj & 3));
  const int projw = jj & 3;
  const int rb = (jj >> 3) * 16;
  const int cb = (jj & 7) * 16;

  int mrow[8]; int lenr[8];
  #pragma unroll
  for(int rt=0;rt<2;rt++)
    #pragma unroll
    for(int r=0;r<4;r++){
      int m = w*32 + rt*16 + lq*4 + r;
      mrow[rt*4+r] = m;
      lenr[rt*4+r] = lengths[m];
    }

  float cst[8], hst[8];
  #pragma unroll
  for(int i=0;i<8;i++){ cst[i]=0.f; hst[i]=0.f; }

  int last_src = -1;

  for(int t=0; t<1024; ++t){
    const unsigned short* hr = (t & 1) ? hb1 : hb0;
    unsigned short*       hw = (t & 1) ? hb0 : hb1;

    // ---- select weights for this step ----
    const unsigned short* Wsrc; int K; const float* bias; int use_x; int xt; int src_id;
    if(t < 512){
      Wsrc = encW; K = KE_; bias = encb; use_x = 1; xt = t; src_id = 0;
    } else {
      int s = t - 512;
      int tf = (s == 0) ? 1 : tfmask[s-1];
      if(tf){ Wsrc = decW; K = KE_; bias = decb;  use_x = 1; xt = (s==0) ? (T_-1) : (s-1); src_id = 1; }
      else  { Wsrc = weff; K = H_;  bias = decbe; use_x = 0; xt = 0;                       src_id = 2; }
    }

    // ---- stage weight strip into LDS when the source changes ----
    if(src_id != last_src){
      #pragma unroll
      for(int row=0; row<16; ++row){
        int off = tid * 8;
        if(off < K){
          int g = row >> 2, c = row & 3;
          short8 v = *(const short8*)(Wsrc + (long)(g*H_ + hc0 + c)*K + off);
          *(short8*)(&wlds[row*LSTR + off]) = v;
        }
      }
      last_src = src_id;
      __syncthreads();
    }

    // ---- GEMM: G[128 x 16strip] ----
    f32x4 acc0 = (f32x4){0.f,0.f,0.f,0.f};
    f32x4 acc1 = (f32x4){0.f,0.f,0.f,0.f};

    const unsigned short* ldsrow = &wlds[lr*LSTR + lq*8];
    const unsigned short* h0p = hr + (long)(w*32 + lr)*H_ + lq*8;
    const unsigned short* h1p = h0p + 16*H_;

    int kbase = 0;
    if(use_x){
      const unsigned short* x0p = xbf + (long)(w*32 + lr)*(T_*I_) + (long)xt*I_ + lq*8;
      const unsigned short* x1p = x0p + (long)16*(T_*I_);
      #pragma unroll
      for(int ks=0; ks<4; ++ks){
        short8 bfrag = *(const short8*)(ldsrow + ks*32);
        short8 a0 = *(const short8*)(x0p + ks*32);
        short8 a1 = *(const short8*)(x1p + ks*32);
        acc0 = __builtin_amdgcn_mfma_f32_16x16x32_bf16(a0, bfrag, acc0, 0,0,0);
        acc1 = __builtin_amdgcn_mfma_f32_16x16x32_bf16(a1, bfrag, acc1, 0,0,0);
      }
      kbase = I_;
    }
    for(int ks=0; ks<32; ++ks){
      short8 bfrag = *(const short8*)(ldsrow + kbase + ks*32);
      short8 a0 = *(const short8*)(h0p + ks*32);
      short8 a1 = *(const short8*)(h1p + ks*32);
      acc0 = __builtin_amdgcn_mfma_f32_16x16x32_bf16(a0, bfrag, acc0, 0,0,0);
      acc1 = __builtin_amdgcn_mfma_f32_16x16x32_bf16(a1, bfrag, acc1, 0,0,0);
    }

    // ---- epilogue: gather 4 gates via shfl, update register state ----
    float bi0=0.f, bi1=0.f, bi2=0.f, bi3=0.f;
    if(lr < 4){
      bi0 = bias[hc]; bi1 = bias[H_+hc]; bi2 = bias[2*H_+hc]; bi3 = bias[3*H_+hc];
    }
    const int c3 = l & 3, bse = l & 48;
    #pragma unroll
    for(int rt=0; rt<2; ++rt){
      #pragma unroll
      for(int r=0; r<4; ++r){
        float v = (rt==0) ? acc0[r] : acc1[r];
        float gi = __shfl(v, bse | (0  + c3), 64);
        float gf = __shfl(v, bse | (4  + c3), 64);
        float gg = __shfl(v, bse | (8  + c3), 64);
        float go = __shfl(v, bse | (12 + c3), 64);
        if(lr < 4){
          const int idx = rt*4 + r;
          const int m = mrow[idx];
          float i_ = sigm(gi + bi0);
          float f_ = sigm(gf + bi1);
          float g_ = tanh_(gg + bi2);
          float o_ = sigm(go + bi3);
          float c2 = f_*cst[idx] + i_*g_;
          float h2 = o_*tanh_(c2);
          if(t < 512){
            int vm = (t < lenr[idx]) ? 1 : 0;
            float hn = vm ? h2 : hst[idx];
            float cn = vm ? c2 : cst[idx];
            hst[idx] = hn; cst[idx] = cn;
            hw[m*H_ + hc] = f2bf(hn);
            dout[ENCOFF + (long)m*(T_*H_) + (long)t*H_ + hc] = vm ? h2 : 0.f;
          } else {
            hst[idx] = h2; cst[idx] = c2;
            hw[m*H_ + hc] = f2bf(h2);
          }
        }
      }
    }

    // ---- decoder projection out_{s-1} = h_{s-1} @ linW^T + linb (off critical path) ----
    if(t >= 513 && projb && w == projw){
      const int s = t - 512;
      f32x4 p = (f32x4){0.f,0.f,0.f,0.f};
      const unsigned short* ha = hr + (long)(rb + lr)*H_ + lq*8;
      const unsigned short* wbp = linwb + (long)(cb + lr)*H_ + lq*8;
      for(int ks=0; ks<32; ++ks){
        short8 af = *(const short8*)(ha  + ks*32);
        short8 bf = *(const short8*)(wbp + ks*32);
        p = __builtin_amdgcn_mfma_f32_16x16x32_bf16(af, bf, p, 0,0,0);
      }
      #pragma unroll
      for(int r=0;r<4;r++){
        dout[(long)(rb + lq*4 + r)*(T_*I_) + (long)(s-1)*I_ + cb + lr] = p[r] + linb[cb+lr];
      }
    }

    // ---- grid barrier ----
    __syncthreads();
    if(tid == 0){
      __threadfence();
      atomicAdd(cnt, 1u);
      const unsigned target = (unsigned)NBLK * (unsigned)(t+1);
      while(__hip_atomic_load(cnt, __ATOMIC_RELAXED, __HIP_MEMORY_SCOPE_AGENT) < target){
        __builtin_amdgcn_s_sleep(1);
      }
      __threadfence();
    }
    __syncthreads();
  }

  // ---- final projection out_{511} from final h (in hb0) ----
  if(projb && w == projw){
    f32x4 p = (f32x4){0.f,0.f,0.f,0.f};
    const unsigned short* ha = hb0 + (long)(rb + lr)*H_ + lq*8;
    const unsigned short* wbp = linwb + (long)(cb + lr)*H_ + lq*8;
    for(int ks=0; ks<32; ++ks){
      short8 af = *(const short8*)(ha  + ks*32);
      short8 bf = *(const short8*)(wbp + ks*32);
      p = __builtin_amdgcn_mfma_f32_16x16x32_bf16(af, bf, p, 0,0,0);
    }
    #pragma unroll
    for(int r=0;r<4;r++){
      dout[(long)(rb + lq*4 + r)*(T_*I_) + (long)(T_-1)*I_ + cb + lr] = p[r] + linb[cb+lr];
    }
  }
}

// ---------------- host ----------------

extern "C" void kernel_launch(void* const* d_in, const int* in_sizes, int n_in,
                              void* d_out, int out_size, void* d_ws, size_t ws_size,
                              hipStream_t stream) {
  const float* x       = (const float*)d_in[0];
  const float* eWih    = (const float*)d_in[1];
  const float* eWhh    = (const float*)d_in[2];
  const float* ebih    = (const float*)d_in[3];
  const float* ebhh    = (const float*)d_in[4];
  const float* dWih    = (const float*)d_in[5];
  const float* dWhh    = (const float*)d_in[6];
  const float* dbih    = (const float*)d_in[7];
  const float* dbhh    = (const float*)d_in[8];
  const float* linW    = (const float*)d_in[9];
  const float* linb    = (const float*)d_in[10];
  const int*   lengths = (const int*)d_in[11];
  const int*   tfmask  = (const int*)d_in[12];
  float* dout = (float*)d_out;

  char* ws = (char*)d_ws;
  size_t off = 0;
  auto alloc = [&](size_t bytes)->char*{ char* p = ws + off; off = (off + bytes + 255) & ~(size_t)255; return p; };
  unsigned short* xbf   = (unsigned short*)alloc((size_t)B_*T_*I_*2);
  unsigned short* encW  = (unsigned short*)alloc((size_t)G4_*KE_*2);
  unsigned short* decW  = (unsigned short*)alloc((size_t)G4_*KE_*2);
  unsigned short* weff  = (unsigned short*)alloc((size_t)G4_*H_*2);
  unsigned short* linwb = (unsigned short*)alloc((size_t)I_*H_*2);
  unsigned short* hb0   = (unsigned short*)alloc((size_t)B_*H_*2);
  unsigned short* hb1   = (unsigned short*)alloc((size_t)B_*H_*2);
  float*          encb  = (float*)alloc((size_t)G4_*4);
  float*          decb  = (float*)alloc((size_t)G4_*4);
  float*          decbe = (float*)alloc((size_t)G4_*4);
  unsigned*       cnt   = (unsigned*)alloc(256);

  // prepass
  k_f32_to_bf16<<<dim3((B_*T_*I_+255)/256), dim3(256), 0, stream>>>(x, xbf, B_*T_*I_);
  k_f32_to_bf16<<<dim3((I_*H_+255)/256),   dim3(256), 0, stream>>>(linW, linwb, I_*H_);
  k_build_wcat<<<dim3(5, G4_), dim3(256), 0, stream>>>(eWih, eWhh, encW);
  k_build_wcat<<<dim3(5, G4_), dim3(256), 0, stream>>>(dWih, dWhh, decW);
  k_build_weff<<<dim3(4, G4_), dim3(256), 0, stream>>>(dWih, dWhh, linW, weff);
  k_build_bias<<<dim3(16), dim3(256), 0, stream>>>(ebih, ebhh, dbih, dbhh, dWih, linb, encb, decb, decbe);
  k_init_state<<<dim3((B_*H_+255)/256), dim3(256), 0, stream>>>(hb0, cnt);

  // persistent cooperative kernel: all 1024 steps
  const unsigned short* encW_c = encW; const unsigned short* decW_c = decW;
  const unsigned short* weff_c = weff; const unsigned short* xbf_c = xbf;
  unsigned short* hb0_p = hb0; unsigned short* hb1_p = hb1;
  const float* encb_c = encb; const float* decb_c = decb; const float* decbe_c = decbe;
  const int* len_c = lengths; const int* tf_c = tfmask;
  const unsigned short* linwb_c = linwb; const float* linb_c = linb;
  float* dout_p = dout; unsigned* cnt_p = cnt;
  void* args[] = {&encW_c, &decW_c, &weff_c, &xbf_c, &hb0_p, &hb1_p,
                  &encb_c, &decb_c, &decbe_c, &len_c, &tf_c,
                  &linwb_c, &linb_c, &dout_p, &cnt_p};
  hipLaunchCooperativeKernel((void*)k_persist, dim3(NBLK), dim3(256), args, 0, stream);
}